// Round 6
// baseline (161.361 us; speedup 1.0000x reference)
//
#include <hip/hip_runtime.h>
#include <hip/hip_fp16.h>

// BackProjectionLinear: out[b,p] = sum_d apod[d] * lerp(sino[b,d], k[p,d], a[p,d]) / 63.5
// B=4, N_DET=128, N_T=2048, pixels=65536.
//
// R6 = R5 with the nontemporal-load compile fix (native ext_vector_type
// instead of HIP_vector_type for __builtin_nontemporal_load).
//
// R5 design: R4 was latency-serialized (HBM 22%, VALU 12%, occ 33%):
// each phase exposed its staging latency at the barrier's vmcnt(0) drain, and
// all 4.19M atomics burst at kernel end.
//  - Ping-pong LDS: 2 x 32KB buffers (4 dets x 2048 t x half2(2 batches)).
//    4 phases = (batch-pair) x (det-half). Phase p+1's staging loads issue
//    BEFORE gather(p) -> latency hidden under gather + barrier.
//  - lut: full 64B line per pixel in regs (8 float4/thread, PXPT=2), loaded
//    once, nontemporal (single-use 64MB stream must not thrash the 4MB L2
//    that keeps sino restages local).
//  - Early atomic emit: b0/b1 partials issued mid-kernel, b2/b3 at end.
//  - bid%16 = octet (bid%8 ~ XCD) -> sino rows L2-pinned per XCD.

#define NB      4
#define NDET    128
#define NT      2048
#define NPIX    65536
#define DBLOCK  8                    // dets per block = one 64B lut line
#define DPH     4                    // dets per phase (det-half)
#define PTILE   1024
#define THREADS 512
#define PXPT    (PTILE / THREADS)    // 2 pixels per thread

typedef float floatx4 __attribute__((ext_vector_type(4)));

__global__ __launch_bounds__(THREADS, 4)
void bp_kernel(const float* __restrict__ sino,
               const float* __restrict__ lut,
               float* __restrict__ out) {
    // two ping-pong buffers: [buf][dl(0..3)][t] half2=(b_even,b_odd). 2x32KB.
    __shared__ __half2 lds[2][DPH][NT];

    const int tid   = threadIdx.x;
    const int octet = blockIdx.x & 15;
    const int tile  = blockIdx.x >> 4;
    const int d0    = octet * DBLOCK;
    const int px0   = tile * PTILE;

    float apod[DBLOCK];
#pragma unroll
    for (int j = 0; j < DBLOCK; ++j) {
        float x = (float)(d0 + j) * (6.28318530717958647692f / 127.0f);
        apod[j] = 0.5f - 0.5f * __cosf(x);
    }

    // ---- full 64B lut line per pixel, once, nontemporal ----
    floatx4 L[PXPT][4];   // L[i][q] = (k,a) x 2 dets for dets d0+2q, d0+2q+1
#pragma unroll
    for (int i = 0; i < PXPT; ++i) {
        const floatx4* lp = (const floatx4*)
            (lut + ((size_t)(px0 + tid + i * THREADS) * NDET + d0) * 2);
#pragma unroll
        for (int q = 0; q < 4; ++q) L[i][q] = __builtin_nontemporal_load(lp + q);
    }

    float acc[PXPT][NB];
#pragma unroll
    for (int i = 0; i < PXPT; ++i)
#pragma unroll
        for (int b = 0; b < NB; ++b) acc[i][b] = 0.0f;

    const floatx4* s4 = (const floatx4*)sino;
    floatx4 ve[DPH], vo[DPH];   // staging registers (8 float4 in flight)

    // phase p: batches b0=(p>>1)*2, b0+1; dets d0+(p&1)*DPH .. +3; buf=p&1
    auto stage_issue = [&](int p) {
        const int b0  = (p >> 1) * 2;
        const int dg0 = d0 + (p & 1) * DPH;
#pragma unroll
        for (int dl = 0; dl < DPH; ++dl) {
            size_t row = ((size_t)b0 * NDET + dg0 + dl) * (NT / 4) + tid;
            ve[dl] = s4[row];
            vo[dl] = s4[row + (size_t)NDET * (NT / 4)];
        }
    };
    auto stage_write = [&](int p) {
        const int buf = p & 1;
#pragma unroll
        for (int dl = 0; dl < DPH; ++dl) {
            __half2* dst = &lds[buf][dl][tid * 4];
            dst[0] = __floats2half2_rn(ve[dl].x, vo[dl].x);
            dst[1] = __floats2half2_rn(ve[dl].y, vo[dl].y);
            dst[2] = __floats2half2_rn(ve[dl].z, vo[dl].z);
            dst[3] = __floats2half2_rn(ve[dl].w, vo[dl].w);
        }
    };
    auto gather = [&](int p) {
        const int b0  = (p >> 1) * 2;
        const int dh  = p & 1;
        const int buf = p & 1;
#pragma unroll
        for (int i = 0; i < PXPT; ++i) {
#pragma unroll
            for (int q2 = 0; q2 < 2; ++q2) {
                floatx4 Lq = L[i][dh * 2 + q2];
#pragma unroll
                for (int h = 0; h < 2; ++h) {
                    float kf = h ? Lq.z : Lq.x;
                    float af = h ? Lq.w : Lq.y;
                    int   dl = q2 * 2 + h;
                    int   j  = dh * DPH + dl;
                    int k = (int)kf;
                    bool valid = (unsigned)k < (unsigned)(NT - 1);
                    float w  = valid ? apod[j] : 0.0f;
                    int  k0  = valid ? k : 0;
                    __half2 s0v = lds[buf][dl][k0];
                    __half2 s1v = lds[buf][dl][k0 + 1];
                    __half2 a2  = __float2half2_rn(af);
                    __half2 sk  = __hfma2(a2, __hsub2(s1v, s0v), s0v);
                    float2  fv  = __half22float2(sk);
                    acc[i][b0 + 0] = fmaf(w, fv.x, acc[i][b0 + 0]);
                    acc[i][b0 + 1] = fmaf(w, fv.y, acc[i][b0 + 1]);
                }
            }
        }
    };
    const float inv_norm = 1.0f / 63.5f;   // sum(apod) == 63.5 exactly
    auto emit = [&](int b) {
#pragma unroll
        for (int i = 0; i < PXPT; ++i) {
            const int px = px0 + tid + i * THREADS;
            atomicAdd(&out[(size_t)b * NPIX + px], acc[i][b] * inv_norm);
        }
    };

    // ---- software pipeline: stage(p+1) in flight under gather(p) ----
    stage_issue(0);
    stage_write(0);          // vmcnt wait on phase-0 loads only
    stage_issue(1);          // in flight across barrier + gather(0)
    __syncthreads();         // buf A ready

    gather(0);
    stage_write(1);
    stage_issue(2);
    __syncthreads();         // buf B ready (all waves done reading A)

    gather(1);
    emit(0); emit(1);        // b0,b1 final -> spread the atomic stream
    stage_write(2);
    stage_issue(3);
    __syncthreads();         // buf A ready (all waves done reading B)

    gather(2);
    stage_write(3);
    __syncthreads();         // buf B ready

    gather(3);
    emit(2); emit(3);
}

extern "C" void kernel_launch(void* const* d_in, const int* in_sizes, int n_in,
                              void* d_out, int out_size, void* d_ws, size_t ws_size,
                              hipStream_t stream) {
    const float* sino = (const float*)d_in[0];
    const float* lut  = (const float*)d_in[1];
    float* out = (float*)d_out;

    (void)hipMemsetAsync(d_out, 0, (size_t)out_size * sizeof(float), stream);

    // 16 octets x 64 pixel tiles = 1024 blocks -> 2 blocks/CU (64KB LDS)
    bp_kernel<<<dim3(1024), dim3(THREADS), 0, stream>>>(sino, lut, out);
}